// Round 1
// baseline (8032.693 us; speedup 1.0000x reference)
//
#include <hip/hip_runtime.h>
#include <cmath>

#define B_ 16
#define T_ 2048
#define D_ 512
#define H_ 512

// ---------------------------------------------------------------------------
// Phase 1: XW[m, n] = x[m, :] @ W_xh[:, n] + bias[n], written into d_out.
// M = B*T = 32768, K = D = 512, N = H = 512. Plain fp32 LDS-tiled GEMM.
// ---------------------------------------------------------------------------
__global__ __launch_bounds__(256) void gemm_xw(
    const float* __restrict__ x,     // [M, K]
    const float* __restrict__ Wxh,   // [K, N]
    const float* __restrict__ bias,  // [N]
    float* __restrict__ out)         // [M, N]
{
    const int tid = threadIdx.x;
    const int m0 = blockIdx.y * 64;
    const int n0 = blockIdx.x * 64;

    __shared__ float As[16][68];  // [k][m], +4 pad keeps 16B align, breaks conflicts
    __shared__ float Bs[16][68];  // [k][n]

    const int tx = tid & 15, ty = tid >> 4;
    float acc[4][4] = {};

    // A tile: 64 rows x 16 k. One float4 per thread.
    const int arow = tid >> 2;
    const int akq  = (tid & 3) * 4;
    // B tile: 16 rows x 64 cols. One float4 per thread.
    const int brow = tid >> 4;
    const int bcol = (tid & 15) * 4;

    for (int k0 = 0; k0 < D_; k0 += 16) {
        float4 a4 = *(const float4*)(x + (size_t)(m0 + arow) * D_ + k0 + akq);
        float4 b4 = *(const float4*)(Wxh + (size_t)(k0 + brow) * H_ + n0 + bcol);
        __syncthreads();  // previous iter done reading LDS
        As[akq + 0][arow] = a4.x;
        As[akq + 1][arow] = a4.y;
        As[akq + 2][arow] = a4.z;
        As[akq + 3][arow] = a4.w;
        *(float4*)(&Bs[brow][bcol]) = b4;
        __syncthreads();
#pragma unroll
        for (int kk = 0; kk < 16; ++kk) {
            float4 av = *(const float4*)(&As[kk][ty * 4]);
            float4 bv = *(const float4*)(&Bs[kk][tx * 4]);
            float a_[4] = {av.x, av.y, av.z, av.w};
            float b_[4] = {bv.x, bv.y, bv.z, bv.w};
#pragma unroll
            for (int i = 0; i < 4; ++i)
#pragma unroll
                for (int j = 0; j < 4; ++j) acc[i][j] += a_[i] * b_[j];
        }
    }

    const float4 bv = *(const float4*)(bias + n0 + tx * 4);
#pragma unroll
    for (int i = 0; i < 4; ++i) {
        const int m = m0 + ty * 4 + i;
        float4 o;
        o.x = acc[i][0] + bv.x;
        o.y = acc[i][1] + bv.y;
        o.z = acc[i][2] + bv.z;
        o.w = acc[i][3] + bv.w;
        *(float4*)(out + (size_t)m * H_ + n0 + tx * 4) = o;
    }
}

// ---------------------------------------------------------------------------
// Phase 2: recurrence. 8 WGs per batch x 16 batches = 128 WGs of 512 threads.
// WG (b, s) owns columns [64s, 64s+64) of h; its W_hh slice (512x64 fp32 =
// 128 KB) lives entirely in registers (64 VGPRs/thread). Each step it
// publishes its 64 h values into d_out[b][t][cols] (which IS the final
// output) and the 8 WGs of a batch rendezvous via monotonic step counters
// in d_ws using agent-scope release/acquire.
// blockIdx = s*16 + b  -> all 8 slices of batch b land on XCD b%8 under the
// round-robin dispatch heuristic (perf only; correctness is scope-based).
// ---------------------------------------------------------------------------
__global__ __launch_bounds__(512) void rnn_rec(
    const float* __restrict__ Whh,    // [D_][H_] row-major
    float* __restrict__ out,          // [B_][T_][H_], pre-filled with XW+b
    unsigned int* __restrict__ flags) // [16][8] stride-32 uints (128B apart)
{
    const int tid = threadIdx.x;
    const int b = blockIdx.x & 15;
    const int s = blockIdx.x >> 4;
    const int j = tid & 63;   // column within slice
    const int p = tid >> 6;   // wave index == row block (rows 64p..64p+63)
    const int col = (s << 6) + j;

    __shared__ float h_lds[H_];
    __shared__ float part[8 * 64];

    // Register-resident W slice: W_reg[r] = Whh[64p + r][col]
    float W_reg[64];
#pragma unroll
    for (int r = 0; r < 64; ++r)
        W_reg[r] = Whh[(size_t)(p * 64 + r) * H_ + col];

    h_lds[tid] = 0.0f;  // h_0 = 0  (tid covers 512)
    __syncthreads();

    float* outb = out + (size_t)b * T_ * H_;

    // xw prefetch pipeline (wave 0 only consumes xw)
    float xw0 = 0.0f, xw1 = 0.0f;
    if (p == 0) {
        xw0 = outb[(size_t)0 * H_ + col];
        xw1 = outb[(size_t)1 * H_ + col];
    }

    unsigned int* myflag = flags + (size_t)(b * 8 + s) * 32;

    for (int t = 0; t < T_; ++t) {
        // ---- partial dot: rows [64p, 64p+64) of column `col` ----
        float acc = 0.0f;
        const float4* hv = (const float4*)(h_lds + (p << 6));
#pragma unroll
        for (int i = 0; i < 16; ++i) {
            float4 h4 = hv[i];
            acc += h4.x * W_reg[4 * i + 0];
            acc += h4.y * W_reg[4 * i + 1];
            acc += h4.z * W_reg[4 * i + 2];
            acc += h4.w * W_reg[4 * i + 3];
        }
        part[tid] = acc;  // part[p*64 + j]
        __syncthreads();

        // ---- reduce 8 partials, tanh, publish (wave 0) ----
        if (p == 0) {
            float ssum = xw0;
#pragma unroll
            for (int q = 0; q < 8; ++q) ssum += part[q * 64 + j];
            const float hnew = tanhf(ssum);
            outb[(size_t)t * H_ + col] = hnew;  // global publish (= output)
            h_lds[col] = hnew;                  // local copy
            xw0 = xw1;
            xw1 = (t + 2 < T_) ? outb[(size_t)(t + 2) * H_ + col] : 0.0f;
        }
        __syncthreads();  // wave0's stores happen-before the release below

        if (tid == 0)
            __hip_atomic_store(myflag, (unsigned)(t + 1), __ATOMIC_RELEASE,
                               __HIP_MEMORY_SCOPE_AGENT);

        // ---- wait for the 7 remote slices of this batch ----
        if (tid < 8 && tid != s) {
            unsigned int* f = flags + (size_t)(b * 8 + tid) * 32;
            while (__hip_atomic_load(f, __ATOMIC_ACQUIRE,
                                     __HIP_MEMORY_SCOPE_AGENT) <
                   (unsigned)(t + 1)) {
            }
        }
        __syncthreads();  // acquire happens-before the gather loads

        // ---- gather remote h slices into LDS (wave p handles slice p) ----
        if (p != s) h_lds[(p << 6) + j] = outb[(size_t)t * H_ + (p << 6) + j];
        __syncthreads();
    }
}

extern "C" void kernel_launch(void* const* d_in, const int* in_sizes, int n_in,
                              void* d_out, int out_size, void* d_ws,
                              size_t ws_size, hipStream_t stream) {
    const float* x    = (const float*)d_in[0];  // [B,T,D]
    const float* Wxh  = (const float*)d_in[1];  // [D,H]
    const float* Whh  = (const float*)d_in[2];  // [H,H]
    const float* bias = (const float*)d_in[3];  // [H]
    // d_in[4] = A, unused in forward
    float* out = (float*)d_out;

    // flags: 16 batches x 8 slices x 32 uints (128B padded) = 16 KB
    hipMemsetAsync(d_ws, 0, 16 * 8 * 32 * sizeof(unsigned int), stream);

    dim3 ggrid(H_ / 64, (B_ * T_) / 64, 1);
    gemm_xw<<<ggrid, 256, 0, stream>>>(x, Wxh, bias, out);

    rnn_rec<<<128, 512, 0, stream>>>(Whh, out, (unsigned int*)d_ws);
}

// Round 2
// 3075.080 us; speedup vs baseline: 2.6122x; 2.6122x over previous
//
#include <hip/hip_runtime.h>
#include <cmath>

#define B_ 16
#define T_ 2048
#define D_ 512
#define H_ 512

// ---------------------------------------------------------------------------
// Phase 1: XW[m, n] = x[m, :] @ W_xh[:, n] + bias[n], written into d_out.
// M = B*T = 32768, K = D = 512, N = H = 512. Plain fp32 LDS-tiled GEMM.
// ---------------------------------------------------------------------------
__global__ __launch_bounds__(256) void gemm_xw(
    const float* __restrict__ x,     // [M, K]
    const float* __restrict__ Wxh,   // [K, N]
    const float* __restrict__ bias,  // [N]
    float* __restrict__ out)         // [M, N]
{
    const int tid = threadIdx.x;
    const int m0 = blockIdx.y * 64;
    const int n0 = blockIdx.x * 64;

    __shared__ float As[16][68];
    __shared__ float Bs[16][68];

    const int tx = tid & 15, ty = tid >> 4;
    float acc[4][4] = {};

    const int arow = tid >> 2;
    const int akq  = (tid & 3) * 4;
    const int brow = tid >> 4;
    const int bcol = (tid & 15) * 4;

    for (int k0 = 0; k0 < D_; k0 += 16) {
        float4 a4 = *(const float4*)(x + (size_t)(m0 + arow) * D_ + k0 + akq);
        float4 b4 = *(const float4*)(Wxh + (size_t)(k0 + brow) * H_ + n0 + bcol);
        __syncthreads();
        As[akq + 0][arow] = a4.x;
        As[akq + 1][arow] = a4.y;
        As[akq + 2][arow] = a4.z;
        As[akq + 3][arow] = a4.w;
        *(float4*)(&Bs[brow][bcol]) = b4;
        __syncthreads();
#pragma unroll
        for (int kk = 0; kk < 16; ++kk) {
            float4 av = *(const float4*)(&As[kk][ty * 4]);
            float4 bv = *(const float4*)(&Bs[kk][tx * 4]);
            float a_[4] = {av.x, av.y, av.z, av.w};
            float b_[4] = {bv.x, bv.y, bv.z, bv.w};
#pragma unroll
            for (int i = 0; i < 4; ++i)
#pragma unroll
                for (int j = 0; j < 4; ++j) acc[i][j] += a_[i] * b_[j];
        }
    }

    const float4 bv = *(const float4*)(bias + n0 + tx * 4);
#pragma unroll
    for (int i = 0; i < 4; ++i) {
        const int m = m0 + ty * 4 + i;
        float4 o;
        o.x = acc[i][0] + bv.x;
        o.y = acc[i][1] + bv.y;
        o.z = acc[i][2] + bv.z;
        o.w = acc[i][3] + bv.w;
        *(float4*)(out + (size_t)m * H_ + n0 + tx * 4) = o;
    }
}

// ---------------------------------------------------------------------------
// Phase 2: recurrence, fence-free.
// 8 WGs per batch x 16 batches. WG (b,s) owns h columns [64s, 64s+64); its
// W_hh slice (512x64 fp32) is register/AGPR-resident. Cross-WG h exchange is
// a single 64-bit RELAXED agent-scope atomic per element: hi32 = tag (t+1),
// lo32 = float bits. One atomic word = data + readiness -> no fences, no L2
// writeback/invalidate per step. Slots double-buffered by tag&1; producer
// lead is bounded to 1 step by the consume-before-produce dependency chain,
// so 2 slots cannot be overrun.
// 2 barriers/step: (1) part[] ready + h_lds reads done, (2) h_lds updated.
// ---------------------------------------------------------------------------
__global__ __launch_bounds__(512) void rnn_rec(
    const float* __restrict__ Whh,           // [H_][H_] row-major
    float* __restrict__ out,                 // [B_][T_][H_], pre-filled XW+b
    unsigned long long* __restrict__ ws)     // [B_][2][H_] packed (tag,val)
{
    const int tid = threadIdx.x;
    const int b = blockIdx.x & 15;
    const int s = blockIdx.x >> 4;
    const int j = tid & 63;   // column within slice
    const int p = tid >> 6;   // wave index == row block (rows 64p..64p+63)
    const int col = (s << 6) + j;

    __shared__ float h_lds[H_];
    __shared__ float part[8 * 64];

    // Register-resident W slice: W_reg[r] = Whh[64p + r][col]
    float W_reg[64];
#pragma unroll
    for (int r = 0; r < 64; ++r)
        W_reg[r] = Whh[(size_t)(p * 64 + r) * H_ + col];

    h_lds[tid] = 0.0f;  // h_0 = 0
    __syncthreads();

    float* outb = out + (size_t)b * T_ * H_;
    unsigned long long* wsb = ws + (size_t)b * 2 * H_;

    // xw prefetch pipeline (wave 0 consumes xw; reads own columns only)
    float xw0 = 0.0f, xw1 = 0.0f;
    if (p == 0) {
        xw0 = outb[(size_t)0 * H_ + col];
        xw1 = outb[(size_t)1 * H_ + col];
    }

    for (int t = 0; t < T_; ++t) {
        // ---- partial dot: rows [64p, 64p+64) of column `col` ----
        float acc = 0.0f;
        const float4* hv = (const float4*)(h_lds + (p << 6));
#pragma unroll
        for (int i = 0; i < 16; ++i) {
            float4 h4 = hv[i];
            acc += h4.x * W_reg[4 * i + 0];
            acc += h4.y * W_reg[4 * i + 1];
            acc += h4.z * W_reg[4 * i + 2];
            acc += h4.w * W_reg[4 * i + 3];
        }
        part[tid] = acc;
        __syncthreads();  // (1) part ready; all waves done reading h_lds(t-1)

        const unsigned int tag = (unsigned int)(t + 1);
        const int slot = (t + 1) & 1;
        unsigned long long* wslot = wsb + (size_t)slot * H_;

        if (p == 0) {
            // ---- reduce 8 partials, tanh, publish ----
            float ssum = xw0;
#pragma unroll
            for (int q = 0; q < 8; ++q) ssum += part[q * 64 + j];
            union { unsigned int u; float f; } cv;
            cv.f = tanhf(ssum);
            // publish to comm buffer FIRST (remote pollers wait on this)
            unsigned long long pv =
                ((unsigned long long)tag << 32) | (unsigned long long)cv.u;
            __hip_atomic_store(wslot + col, pv, __ATOMIC_RELAXED,
                               __HIP_MEMORY_SCOPE_AGENT);
            outb[(size_t)t * H_ + col] = cv.f;  // final output (plain, cached)
            h_lds[col] = cv.f;                  // local copy for next step
            xw0 = xw1;
            xw1 = (t + 2 < T_) ? outb[(size_t)(t + 2) * H_ + col] : 0.0f;
        } else {
            // ---- gather one remote slice: wave p -> slice p, except wave s
            // (whose slice is local) covers slice 0 for wave 0 ----
            const int q = (p == s) ? 0 : p;
            unsigned long long* src = wslot + (q << 6) + j;
            unsigned long long v;
            do {
                v = __hip_atomic_load(src, __ATOMIC_RELAXED,
                                      __HIP_MEMORY_SCOPE_AGENT);
            } while ((unsigned int)(v >> 32) < tag);
            union { unsigned int u; float f; } cv;
            cv.u = (unsigned int)v;
            h_lds[(q << 6) + j] = cv.f;
        }
        __syncthreads();  // (2) h_lds now holds h_t
    }
}

extern "C" void kernel_launch(void* const* d_in, const int* in_sizes, int n_in,
                              void* d_out, int out_size, void* d_ws,
                              size_t ws_size, hipStream_t stream) {
    const float* x    = (const float*)d_in[0];  // [B,T,D]
    const float* Wxh  = (const float*)d_in[1];  // [D,H]
    const float* Whh  = (const float*)d_in[2];  // [H,H]
    const float* bias = (const float*)d_in[3];  // [H]
    // d_in[4] = A, unused in forward
    float* out = (float*)d_out;

    // comm buffer: [16][2][512] x 8B = 128 KB; tags must start at 0
    hipMemsetAsync(d_ws, 0, (size_t)B_ * 2 * H_ * sizeof(unsigned long long),
                   stream);

    dim3 ggrid(H_ / 64, (B_ * T_) / 64, 1);
    gemm_xw<<<ggrid, 256, 0, stream>>>(x, Wxh, bias, out);

    rnn_rec<<<128, 512, 0, stream>>>(Whh, out, (unsigned long long*)d_ws);
}